// Round 11
// baseline (811.927 us; speedup 1.0000x reference)
//
#include <hip/hip_runtime.h>

typedef __attribute__((ext_vector_type(8))) _Float16 half8;
typedef __attribute__((ext_vector_type(4))) _Float16 half4;
typedef __attribute__((ext_vector_type(16))) float floatx16;

#define DI __device__ __forceinline__

DI void gl_lds16(const void* g, void* l) {
    __builtin_amdgcn_global_load_lds(
        (__attribute__((address_space(1))) void*)(g),
        (__attribute__((address_space(3))) void*)(l), 16, 0, 0);
}

// Interleaved layout everywhere: per (row, ci32-block): [32 hi halfs | 32 lo halfs] = 128 B line.
// LDS slot swizzle: content chunk c of row r lives at slot c ^ (r&7) ^ (((r>>3)&1)<<2)
//   (write side: lc = sl ^ rl ^ ((wid&1)<<2); 32-row fragment reads then hit each slot 2-way = free)

// ------------- merged prep: weight split (b<1024) + input split (b>=1024) -------------
__global__ __launch_bounds__(256) void prep_split(
        const float* __restrict__ w1, _Float16* __restrict__ w1I,
        const float* __restrict__ w2, _Float16* __restrict__ w2I,
        const float* __restrict__ in, _Float16* __restrict__ oI,
        float* __restrict__ zp) {
    __shared__ float L[13824];
    const int b = blockIdx.x;
    const int tid = threadIdx.x;
    if (b == 0 && tid < 64) zp[tid] = 0.0f;      // 256B zero page for conv DMA OOB
    if (b < 512) {
        const float* src = w1 + (size_t)b * 6912;     // [ci=256][tap=27]
        for (int idx = tid; idx < 6912; idx += 256) L[idx] = src[idx] * 64.0f;
        __syncthreads();
        for (int c = tid; c < 864; c += 256) {        // 27 taps x 32 octets
            const int tap = c >> 5, o = c & 31;
            half8 h, l;
#pragma unroll
            for (int j = 0; j < 8; ++j) {
                const float x = L[(o * 8 + j) * 27 + tap];
                const _Float16 hh = (_Float16)x;
                h[j] = hh; l[j] = (_Float16)(x - (float)hh);
            }
            const size_t off = (size_t)b * 13824 + (size_t)(tap * 8 + (o >> 2)) * 64 + (o & 3) * 8;
            *(half8*)&w1I[off] = h;
            *(half8*)&w1I[off + 32] = l;
        }
    } else if (b < 1024) {
        const float* src = w2 + (size_t)(b - 512) * 13824;   // [ci=512][tap=27]
        for (int idx = tid; idx < 13824; idx += 256) L[idx] = src[idx] * 64.0f;
        __syncthreads();
        for (int c = tid; c < 1728; c += 256) {       // 27 taps x 64 octets
            const int tap = c >> 6, o = c & 63;
            half8 h, l;
#pragma unroll
            for (int j = 0; j < 8; ++j) {
                const float x = L[(o * 8 + j) * 27 + tap];
                const _Float16 hh = (_Float16)x;
                h[j] = hh; l[j] = (_Float16)(x - (float)hh);
            }
            const size_t off = (size_t)(b - 512) * 27648 + (size_t)(tap * 16 + (o >> 2)) * 64 + (o & 3) * 8;
            *(half8*)&w2I[off] = h;
            *(half8*)&w2I[off + 32] = l;
        }
    } else {
        const int idx = b - 1024;             // 0..2047
        const int hb = idx & 1;               // ci half
        const int s0 = (idx >> 1) * 64;       // spatial tile
        const int cil = tid >> 1, part = tid & 1;
        const float* src = in + (size_t)(hb * 128 + cil) * 65536 + s0 + part * 32;
        float v[32];
#pragma unroll
        for (int q = 0; q < 8; ++q) *(float4*)(v + q * 4) = *(const float4*)(src + q * 4);
#pragma unroll
        for (int j = 0; j < 32; ++j) L[cil * 65 + part * 32 + j] = v[j];
        __syncthreads();
#pragma unroll
        for (int k = 0; k < 4; ++k) {         // 64 sp x 16 local octets
            const int c = tid + k * 256;
            const int sp = c >> 4, ol = c & 15;
            half8 h, l;
#pragma unroll
            for (int j = 0; j < 8; ++j) {
                const float x = L[(ol * 8 + j) * 65 + sp];
                const _Float16 hh = (_Float16)x;
                h[j] = hh; l[j] = (_Float16)(x - (float)hh);
            }
            const int og = hb * 16 + ol;
            const size_t off = (size_t)(s0 + sp) * 512 + (size_t)(og >> 2) * 64 + (og & 3) * 8;
            *(half8*)&oI[off] = h;
            *(half8*)&oI[off + 32] = l;
        }
    }
}

// ---------- conv1: 32x32x16 MFMA, A+B dbuf DMA, B-frag prefetch, row-bit3 XOR swizzle ----------
// grid n (0..511): XCD band n&7 = t>>3  ->  same-t blocks share an XCD's L2
__global__ __launch_bounds__(256, 2) void conv1_mfma(
        const _Float16* __restrict__ xI, const _Float16* __restrict__ wI,
        const float* __restrict__ b1, const _Float16* __restrict__ zp,
        _Float16* __restrict__ yI) {
    __shared__ __align__(16) _Float16 A2[2][128 * 64];   // 32 KB
    __shared__ __align__(16) _Float16 B2[2][128 * 64];   // 32 KB (64 KB total, 2 blocks/CU)
    const int tid = threadIdx.x;
    const int n_ = blockIdx.x;
    const int t = ((n_ & 7) << 3) | ((n_ >> 3) & 7);   // 0..63
    const int co_blk = (n_ >> 6) & 3;                  // 0..3
    const int h0 = ((n_ >> 8) & 1) * 8;                // 0 or 8
    const int wid = tid >> 6, lane = tid & 63;
    const int wm = wid & 1, wn = wid >> 1;             // 2x2 wave grid, 64x64 tile each
    const int r5 = lane & 31, h5 = lane >> 5;
    const int xb = (r5 & 7) ^ (((r5 >> 3) & 1) << 2);  // read-side slot XOR
    const int cshh0 = (h5 ^ xb) * 8;                   // kk=0 hi slot (halfs); lo = ^32
    const int cshh1 = ((2 + h5) ^ xb) * 8;             // kk=1 hi slot
    const int sl = lane & 7, rl = lane >> 3;
    const int lc = sl ^ rl ^ ((wid & 1) << 2);         // write-side content chunk

    const _Float16* wA[4]; const _Float16* bB[4];
    int dstq[4]; bool hok[4], wok[4];
    const size_t wbo = (size_t)co_blk * 128 * 13824;
#pragma unroll
    for (int q = 0; q < 4; ++q) {
        const int row = (q * 4 + wid) * 8 + rl;    // A: co row / B: n row
        wA[q] = wI + wbo + (size_t)row * 13824 + lc * 8;
        dstq[q] = (q * 4 + wid) * 512 + lane * 8;
        const int h = h0 + (row >> 4), w = row & 15;
        const int ih2 = 2 * h - 1, iw2 = 2 * w - 1;
        hok[q] = (ih2 >= 0); wok[q] = (iw2 >= 0);  // only edge underflow possible
        bB[q] = xI + (ptrdiff_t)(ih2 * 32 + iw2) * 512 + lc * 8;
    }
    const _Float16* zpl = zp + lc * 8;

    floatx16 acc[2][2];
#pragma unroll
    for (int i = 0; i < 2; ++i)
#pragma unroll
        for (int j = 0; j < 2; ++j)
#pragma unroll
            for (int e = 0; e < 16; ++e) acc[i][j][e] = 0.0f;

    auto stageA = [&](int kt, int cb, int KH, int KW, _Float16* Ad) {
        const size_t ab = (size_t)(((kt * 9 + KH * 3 + KW) * 8 + cb) * 64);
#pragma unroll
        for (int q = 0; q < 4; ++q) gl_lds16(wA[q] + ab, &Ad[dstq[q]]);
    };
    auto stageB = [&](int kt, int cb, int KH, int KW, _Float16* Bd) {
        const int it = t + kt - 1;                      // wave-uniform
        const bool tok = ((unsigned)it < 64u);
        const ptrdiff_t boff = (ptrdiff_t)it * 524288 + KH * 16384 + KW * 512 + cb * 64;
#pragma unroll
        for (int q = 0; q < 4; ++q) {
            const bool ok = tok && (KH > 0 || hok[q]) && (KW > 0 || wok[q]);
            gl_lds16(ok ? (bB[q] + boff) : zpl, &Bd[dstq[q]]);
        }
    };

    // B fragments for CURRENT phase (prefetched during previous phase)
    half8 b_h[2][2], b_l[2][2];   // [kk][ni]

    stageA(0, 0, 0, 0, A2[0]);
    stageB(0, 0, 0, 0, B2[0]);
    asm volatile("s_waitcnt vmcnt(0)" ::: "memory");
    __builtin_amdgcn_s_barrier();
#pragma unroll
    for (int ni = 0; ni < 2; ++ni) {
        const _Float16* pb = &B2[0][(wn * 64 + ni * 32 + r5) * 64];
        b_h[0][ni] = *(const half8*)&pb[cshh0]; b_l[0][ni] = *(const half8*)&pb[cshh0 ^ 32];
        b_h[1][ni] = *(const half8*)&pb[cshh1]; b_l[1][ni] = *(const half8*)&pb[cshh1 ^ 32];
    }

    for (int o = 0; o < 24; ++o) {                 // o = cb*3 + kt
        const int cb = o / 3, kt = o - cb * 3;
        const int o1 = o + 1;
        const int cb1 = o1 / 3, kt1 = o1 - cb1 * 3;   // o==23 -> dummy-but-valid addresses
#pragma unroll
        for (int j = 0; j < 9; ++j) {              // j = kh*3 + kw (compile-time)
            const int par = (o + j) & 1;
            if (j < 8) {
                stageA(kt, cb, (j + 1) / 3, (j + 1) % 3, A2[par ^ 1]);
                stageB(kt, cb, (j + 1) / 3, (j + 1) % 3, B2[par ^ 1]);
            } else {
                stageA(kt1, cb1, 0, 0, A2[par ^ 1]);
                stageB(kt1, cb1, 0, 0, B2[par ^ 1]);
            }
            const _Float16* Ab = A2[par];
            half8 a_h[2][2], a_l[2][2];            // [mi][kk]
#pragma unroll
            for (int mi = 0; mi < 2; ++mi) {
                const _Float16* pa = &Ab[(wm * 64 + mi * 32 + r5) * 64];
                a_h[mi][0] = *(const half8*)&pa[cshh0]; a_l[mi][0] = *(const half8*)&pa[cshh0 ^ 32];
                a_h[mi][1] = *(const half8*)&pa[cshh1]; a_l[mi][1] = *(const half8*)&pa[cshh1 ^ 32];
            }
            __builtin_amdgcn_s_setprio(1);
#pragma unroll
            for (int kk = 0; kk < 2; ++kk) {
#pragma unroll
                for (int mi = 0; mi < 2; ++mi)
#pragma unroll
                    for (int ni = 0; ni < 2; ++ni)
                        acc[mi][ni] = __builtin_amdgcn_mfma_f32_32x32x16_f16(
                            a_h[mi][kk], b_h[kk][ni], acc[mi][ni], 0, 0, 0);
#pragma unroll
                for (int mi = 0; mi < 2; ++mi)
#pragma unroll
                    for (int ni = 0; ni < 2; ++ni)
                        acc[mi][ni] = __builtin_amdgcn_mfma_f32_32x32x16_f16(
                            a_h[mi][kk], b_l[kk][ni], acc[mi][ni], 0, 0, 0);
#pragma unroll
                for (int mi = 0; mi < 2; ++mi)
#pragma unroll
                    for (int ni = 0; ni < 2; ++ni)
                        acc[mi][ni] = __builtin_amdgcn_mfma_f32_32x32x16_f16(
                            a_l[mi][kk], b_h[kk][ni], acc[mi][ni], 0, 0, 0);
            }
            __builtin_amdgcn_s_setprio(0);
            asm volatile("s_waitcnt vmcnt(0)" ::: "memory");
            __builtin_amdgcn_s_barrier();
            // prefetch B fragments for phase p+1 from the just-drained buffer
            const _Float16* Bn = B2[par ^ 1];
#pragma unroll
            for (int ni = 0; ni < 2; ++ni) {
                const _Float16* pb = &Bn[(wn * 64 + ni * 32 + r5) * 64];
                b_h[0][ni] = *(const half8*)&pb[cshh0]; b_l[0][ni] = *(const half8*)&pb[cshh0 ^ 32];
                b_h[1][ni] = *(const half8*)&pb[cshh1]; b_l[1][ni] = *(const half8*)&pb[cshh1 ^ 32];
            }
        }
    }

    // epilogue: 32x32 C/D map col=lane&31, row=(r&3)+8*(r>>2)+4*h5
#pragma unroll
    for (int mi = 0; mi < 2; ++mi)
#pragma unroll
        for (int ni = 0; ni < 2; ++ni) {
            const int n = wn * 64 + ni * 32 + r5;
            const int h = h0 + (n >> 4), w = n & 15;
            const size_t spb = ((size_t)t * 256 + h * 16 + w) * 1024;
#pragma unroll
            for (int g = 0; g < 4; ++g) {
                const int co = co_blk * 128 + wm * 64 + mi * 32 + g * 8 + h5 * 4;
                const float4 bv = *(const float4*)&b1[co];
                half4 hv, lv;
#pragma unroll
                for (int r = 0; r < 4; ++r) {
                    const float bb = (r == 0) ? bv.x : (r == 1) ? bv.y : (r == 2) ? bv.z : bv.w;
                    const float v = acc[mi][ni][g * 4 + r] * 0.015625f + bb;
                    const _Float16 hb = (_Float16)v;
                    hv[r] = hb;
                    lv[r] = (_Float16)(v - (float)hb);
                }
                const size_t base = spb + (size_t)(co >> 5) * 64 + (co & 31);
                *(half4*)(yI + base) = hv;
                *(half4*)(yI + base + 32) = lv;
            }
        }
}

// ---------- conv2: 32x32x16 MFMA, same schedule, K-split 4, XCD-banded ----------
// grid n (0..511): XCD band n&7 = tp>>2 -> same-tp blocks (all co, ks) share an XCD's L2
__global__ __launch_bounds__(256, 2) void conv2_mfma(
        const _Float16* __restrict__ xI, const _Float16* __restrict__ wI,
        const _Float16* __restrict__ zp,
        float* __restrict__ x2p) {
    __shared__ __align__(16) _Float16 A2[2][128 * 64];
    __shared__ __align__(16) _Float16 B2[2][128 * 64];
    const int tid = threadIdx.x;
    const int n_ = blockIdx.x;
    const int tp = ((n_ & 7) << 2) | ((n_ >> 3) & 3);  // 0..31
    const int co_blk = (n_ >> 5) & 3;                  // 0..3
    const int ks = (n_ >> 7) & 3;                      // 0..3
    const int wid = tid >> 6, lane = tid & 63;
    const int wm = wid & 1, wn = wid >> 1;
    const int r5 = lane & 31, h5 = lane >> 5;
    const int xb = (r5 & 7) ^ (((r5 >> 3) & 1) << 2);
    const int cshh0 = (h5 ^ xb) * 8;
    const int cshh1 = ((2 + h5) ^ xb) * 8;
    const int sl = lane & 7, rl = lane >> 3;
    const int lc = sl ^ rl ^ ((wid & 1) << 2);

    const _Float16* wA[4]; const _Float16* bB[4];
    int dstq[4], itv[4]; bool hok[4], wok[4];
    const size_t wbo = (size_t)co_blk * 128 * 27648;
#pragma unroll
    for (int q = 0; q < 4; ++q) {
        const int row = (q * 4 + wid) * 8 + rl;
        wA[q] = wI + wbo + (size_t)row * 27648 + lc * 8;
        dstq[q] = (q * 4 + wid) * 512 + lane * 8;
        const int sp = row & 63;
        itv[q] = tp * 2 + (row >> 6) - 1;
        const int ih2 = 2 * (sp >> 3) - 1, iw2 = 2 * (sp & 7) - 1;
        hok[q] = (ih2 >= 0); wok[q] = (iw2 >= 0);
        bB[q] = xI + (ptrdiff_t)((itv[q] * 256 + ih2 * 16 + iw2) * 1024) + lc * 8;
    }
    const _Float16* zpl = zp + lc * 8;

    floatx16 acc[2][2];
#pragma unroll
    for (int i = 0; i < 2; ++i)
#pragma unroll
        for (int j = 0; j < 2; ++j)
#pragma unroll
            for (int e = 0; e < 16; ++e) acc[i][j][e] = 0.0f;

    auto stageA = [&](int kt, int cb, int KH, int KW, _Float16* Ad) {
        const size_t ab = (size_t)(((kt * 9 + KH * 3 + KW) * 16 + cb) * 64);
#pragma unroll
        for (int q = 0; q < 4; ++q) gl_lds16(wA[q] + ab, &Ad[dstq[q]]);
    };
    auto stageB = [&](int kt, int cb, int KH, int KW, _Float16* Bd) {
        const ptrdiff_t boff = (ptrdiff_t)kt * 262144 + KH * 16384 + KW * 1024 + cb * 64;
#pragma unroll
        for (int q = 0; q < 4; ++q) {
            const bool ok = ((unsigned)(itv[q] + kt) < 64u)
                         && (KH > 0 || hok[q]) && (KW > 0 || wok[q]);
            gl_lds16(ok ? (bB[q] + boff) : zpl, &Bd[dstq[q]]);
        }
    };

    half8 b_h[2][2], b_l[2][2];

    stageA(0, ks * 4, 0, 0, A2[0]);
    stageB(0, ks * 4, 0, 0, B2[0]);
    asm volatile("s_waitcnt vmcnt(0)" ::: "memory");
    __builtin_amdgcn_s_barrier();
#pragma unroll
    for (int ni = 0; ni < 2; ++ni) {
        const _Float16* pb = &B2[0][(wn * 64 + ni * 32 + r5) * 64];
        b_h[0][ni] = *(const half8*)&pb[cshh0]; b_l[0][ni] = *(const half8*)&pb[cshh0 ^ 32];
        b_h[1][ni] = *(const half8*)&pb[cshh1]; b_l[1][ni] = *(const half8*)&pb[cshh1 ^ 32];
    }

    for (int o = 0; o < 12; ++o) {
        const int kt = o % 3, cb = ks * 4 + o / 3;
        const int o1 = o + 1;
        const int kt1 = o1 % 3, cb1 = ks * 4 + o1 / 3;   // o==11 -> dummy-but-valid
#pragma unroll
        for (int j = 0; j < 9; ++j) {
            const int par = (o + j) & 1;
            if (j < 8) {
                stageA(kt, cb, (j + 1) / 3, (j + 1) % 3, A2[par ^ 1]);
                stageB(kt, cb, (j + 1) / 3, (j + 1) % 3, B2[par ^ 1]);
            } else {
                stageA(kt1, cb1, 0, 0, A2[par ^ 1]);
                stageB(kt1, cb1, 0, 0, B2[par ^ 1]);
            }
            const _Float16* Ab = A2[par];
            half8 a_h[2][2], a_l[2][2];
#pragma unroll
            for (int mi = 0; mi < 2; ++mi) {
                const _Float16* pa = &Ab[(wm * 64 + mi * 32 + r5) * 64];
                a_h[mi][0] = *(const half8*)&pa[cshh0]; a_l[mi][0] = *(const half8*)&pa[cshh0 ^ 32];
                a_h[mi][1] = *(const half8*)&pa[cshh1]; a_l[mi][1] = *(const half8*)&pa[cshh1 ^ 32];
            }
            __builtin_amdgcn_s_setprio(1);
#pragma unroll
            for (int kk = 0; kk < 2; ++kk) {
#pragma unroll
                for (int mi = 0; mi < 2; ++mi)
#pragma unroll
                    for (int ni = 0; ni < 2; ++ni)
                        acc[mi][ni] = __builtin_amdgcn_mfma_f32_32x32x16_f16(
                            a_h[mi][kk], b_h[kk][ni], acc[mi][ni], 0, 0, 0);
#pragma unroll
                for (int mi = 0; mi < 2; ++mi)
#pragma unroll
                    for (int ni = 0; ni < 2; ++ni)
                        acc[mi][ni] = __builtin_amdgcn_mfma_f32_32x32x16_f16(
                            a_h[mi][kk], b_l[kk][ni], acc[mi][ni], 0, 0, 0);
#pragma unroll
                for (int mi = 0; mi < 2; ++mi)
#pragma unroll
                    for (int ni = 0; ni < 2; ++ni)
                        acc[mi][ni] = __builtin_amdgcn_mfma_f32_32x32x16_f16(
                            a_l[mi][kk], b_h[kk][ni], acc[mi][ni], 0, 0, 0);
            }
            __builtin_amdgcn_s_setprio(0);
            asm volatile("s_waitcnt vmcnt(0)" ::: "memory");
            __builtin_amdgcn_s_barrier();
            const _Float16* Bn = B2[par ^ 1];
#pragma unroll
            for (int ni = 0; ni < 2; ++ni) {
                const _Float16* pb = &Bn[(wn * 64 + ni * 32 + r5) * 64];
                b_h[0][ni] = *(const half8*)&pb[cshh0]; b_l[0][ni] = *(const half8*)&pb[cshh0 ^ 32];
                b_h[1][ni] = *(const half8*)&pb[cshh1]; b_l[1][ni] = *(const half8*)&pb[cshh1 ^ 32];
            }
        }
    }

#pragma unroll
    for (int mi = 0; mi < 2; ++mi)
#pragma unroll
        for (int ni = 0; ni < 2; ++ni) {
            const int n = wn * 64 + ni * 32 + r5;
            const size_t rb = ((size_t)ks * 4096 + tp * 128 + n) * 512;
#pragma unroll
            for (int g = 0; g < 4; ++g) {
                const int co = co_blk * 128 + wm * 64 + mi * 32 + g * 8 + h5 * 4;
                float4 v;
                v.x = acc[mi][ni][g * 4 + 0]; v.y = acc[mi][ni][g * 4 + 1];
                v.z = acc[mi][ni][g * 4 + 2]; v.w = acc[mi][ni][g * 4 + 3];
                *(float4*)&x2p[rb + co] = v;
            }
        }
}

// ------------- fused feat (K-split sum + spatial max + bias) and head matvec -------------
__global__ __launch_bounds__(256) void feat_head(
        const float* __restrict__ x2p, const float* __restrict__ b2,
        const float* __restrict__ sw, const float* __restrict__ sb,
        const float* __restrict__ dw, const float* __restrict__ db,
        float* __restrict__ scoreL, float* __restrict__ deltaL) {
    __shared__ float fr[512];
    __shared__ float partial[32][8];
    const int t = blockIdx.x, tid = threadIdx.x;
#pragma unroll
    for (int cc = 0; cc < 2; ++cc) {
        const int c = tid + cc * 256;
        float mx = -3.4e38f;
        for (int sp = 0; sp < 64; ++sp) {
            const size_t ng = (size_t)t * 64 + sp;
            const float s = x2p[ng * 512 + c]
                          + x2p[((size_t)4096 + ng) * 512 + c]
                          + x2p[((size_t)8192 + ng) * 512 + c]
                          + x2p[((size_t)12288 + ng) * 512 + c];
            mx = fmaxf(mx, s);
        }
        fr[c] = mx * 0.015625f + b2[c];
    }
    __syncthreads();
    const int o = tid & 31, part = tid >> 5;
    const float* wrow = (o < 16) ? (sw + (size_t)o * 512) : (dw + (size_t)(o - 16) * 512);
    float s = 0.f;
    const int j0 = part * 64;
#pragma unroll 16
    for (int j = 0; j < 64; ++j) s += wrow[j0 + j] * fr[j0 + j];
    partial[o][part] = s;
    __syncthreads();
    if (tid < 32) {
        float tot = 0.f;
#pragma unroll
        for (int p = 0; p < 8; ++p) tot += partial[tid][p];
        tot += (tid < 16) ? sb[tid] : db[tid - 16];
        if (tid < 16) scoreL[tid * 64 + t] = tot;
        else deltaL[(tid - 16) * 64 + t] = tot;
    }
}

// ------------- NMS + labels + losses: SINGLE WAVE (64 lanes), no barriers -------------
__global__ void nms_loss_kernel(const float* __restrict__ scoreL,
                                const float* __restrict__ deltaL,
                                const float* __restrict__ gt,
                                const int* __restrict__ video_len,
                                float* __restrict__ out) {
    const int lane = threadIdx.x & 63;
    float gsv[8], gev[8];
#pragma unroll
    for (int g = 0; g < 8; ++g) { gsv[g] = gt[2 * g]; gev[g] = gt[2 * g + 1]; }
    const float center = ((float)lane + 0.5f) * 8.0f;
    float psv[8], pev[8], fg[8], l0v[8], l1v[8], dcv[8], dlv[8];
#pragma unroll
    for (int j = 0; j < 8; ++j) {
        const float s0 = scoreL[j * 64 + lane], s1 = scoreL[(8 + j) * 64 + lane];
        const float mm = fmaxf(s0, s1);
        const float lse = mm + logf(expf(s0 - mm) + expf(s1 - mm));
        l0v[j] = s0 - lse; l1v[j] = s1 - lse;
        const float dc = deltaL[j * 64 + lane], dl = deltaL[(8 + j) * 64 + lane];
        dcv[j] = dc; dlv[j] = dl;
        const float alen = 8.0f * (float)(1 << j);
        const float pc = center + dc * alen;
        const float pl = alen * expf(fminf(fmaxf(dl, -10.0f), 10.0f));
        const float ps = fminf(fmaxf(pc - pl * 0.5f, 0.0f), 512.0f);
        const float pe = fminf(fmaxf(pc + pl * 0.5f, 0.0f), 512.0f);
        psv[j] = ps; pev[j] = pe;
        fg[j] = ((pe - ps) >= 4.0f) ? expf(l1v[j]) : -1e9f;
    }
    for (int itn = 0; itn < 100; ++itn) {
        float v = fg[0]; int idx = lane;
#pragma unroll
        for (int j = 1; j < 8; ++j) if (fg[j] > v) { v = fg[j]; idx = lane + 64 * j; }
#pragma unroll
        for (int off = 32; off > 0; off >>= 1) {
            const float ov = __shfl_down(v, off);
            const int oi = __shfl_down(idx, off);
            if (ov > v || (ov == v && oi < idx)) { v = ov; idx = oi; }
        }
        v = __shfl(v, 0); idx = __shfl(idx, 0);
        const int wj = idx >> 6, wl = idx & 63;
        float bw0 = 0.f, bw1 = 0.f;
#pragma unroll
        for (int j = 0; j < 8; ++j) if (j == wj) { bw0 = psv[j]; bw1 = pev[j]; }
        const float b0 = __shfl(bw0, wl);
        const float b1 = __shfl(bw1, wl);
        if (lane == 0) {
            const bool kept = v > -5e8f;
            out[2 * itn] = kept ? b0 : 0.0f;
            out[2 * itn + 1] = kept ? b1 : 0.0f;
            out[200 + itn] = kept ? v : 0.0f;
        }
#pragma unroll
        for (int j = 0; j < 8; ++j) {
            const int n = lane + 64 * j;
            const float inter = fmaxf(fminf(b1, pev[j]) - fmaxf(b0, psv[j]), 0.0f);
            const float uni = (b1 - b0) + (pev[j] - psv[j]) - inter;
            const float iou = inter / fmaxf(uni, 1e-6f);
            if (iou > 0.7f || n == idx) fg[j] = -1e9f;
        }
    }
    int labv[8], aggv[8];
#pragma unroll
    for (int j = 0; j < 8; ++j) {
        const float alen = 8.0f * (float)(1 << j);
        const float as_ = center - alen * 0.5f, ae_ = center + alen * 0.5f;
        float mx = -1.0f; int ag = 0;
#pragma unroll
        for (int g = 0; g < 8; ++g) {
            const float inter = fmaxf(fminf(ae_, gev[g]) - fmaxf(as_, gsv[g]), 0.0f);
            const float uni = (ae_ - as_) + (gev[g] - gsv[g]) - inter;
            const float iou = inter / fmaxf(uni, 1e-6f);
            if (iou > mx) { mx = iou; ag = g; }
        }
        labv[j] = (mx < 0.3f) ? 0 : ((mx >= 0.7f) ? 1 : -1);
        aggv[j] = ag;
    }
    for (int g = 0; g < 8; ++g) {
        float v = -1.0f; int idx = 0;
#pragma unroll
        for (int j = 0; j < 8; ++j) {
            const int n = lane + 64 * j;
            const float alen = 8.0f * (float)(1 << j);
            const float as_ = center - alen * 0.5f, ae_ = center + alen * 0.5f;
            const float inter = fmaxf(fminf(ae_, gev[g]) - fmaxf(as_, gsv[g]), 0.0f);
            const float uni = (ae_ - as_) + (gev[g] - gsv[g]) - inter;
            const float iou = inter / fmaxf(uni, 1e-6f);
            if (iou > v || (iou == v && n < idx)) { v = iou; idx = n; }
        }
#pragma unroll
        for (int off = 32; off > 0; off >>= 1) {
            const float ov = __shfl_down(v, off);
            const int oi = __shfl_down(idx, off);
            if (ov > v || (ov == v && oi < idx)) { v = ov; idx = oi; }
        }
        idx = __shfl(idx, 0);
#pragma unroll
        for (int j = 0; j < 8; ++j)
            if (lane == (idx & 63) && j == (idx >> 6)) labv[j] = 1;
    }
    const float vl = (float)video_len[0];
    float nll_s = 0.f, msk_s = 0.f, reg_s = 0.f, pos_s = 0.f;
#pragma unroll
    for (int j = 0; j < 8; ++j) {
        const float alen = 8.0f * (float)(1 << j);
        const float as_ = center - alen * 0.5f, ae_ = center + alen * 0.5f;
        int l = labv[j];
        if (!((as_ >= 0.0f) && (ae_ <= vl))) l = -1;
        if (l >= 0) {
            msk_s += 1.0f;
            nll_s -= (l == 1) ? l1v[j] : l0v[j];
            if (l == 1) {
                pos_s += 1.0f;
                float gcv = 0.f, glv = 0.f;
#pragma unroll
                for (int g = 0; g < 8; ++g)
                    if (g == aggv[j]) {
                        gcv = (gsv[g] + gev[g]) * 0.5f;
                        glv = fmaxf(gev[g] - gsv[g], 1e-6f);
                    }
                const float r0 = (gcv - center) / alen;
                const float r1 = logf(glv / alen);
                const float d0 = dcv[j] - r0, d1 = dlv[j] - r1;
                float s = (fabsf(d0) < 1.0f) ? (0.5f * d0 * d0) : (fabsf(d0) - 0.5f);
                s += (fabsf(d1) < 1.0f) ? (0.5f * d1 * d1) : (fabsf(d1) - 0.5f);
                reg_s += s;
            }
        }
    }
    float sums[4] = {nll_s, msk_s, reg_s, pos_s};
#pragma unroll
    for (int k = 0; k < 4; ++k)
#pragma unroll
        for (int off = 32; off > 0; off >>= 1) sums[k] += __shfl_down(sums[k], off);
    if (lane == 0) {
        out[300] = sums[0] / fmaxf(sums[1], 1.0f);
        out[301] = sums[2] / fmaxf(sums[3], 1.0f);
    }
}

extern "C" void kernel_launch(void* const* d_in, const int* in_sizes, int n_in,
                              void* d_out, int out_size, void* d_ws, size_t ws_size,
                              hipStream_t stream) {
    const float* base_feat = (const float*)d_in[0];
    const float* gt        = (const float*)d_in[1];
    const int*   video_len = (const int*)d_in[2];
    const float* w1        = (const float*)d_in[3];
    const float* b1        = (const float*)d_in[4];
    const float* w2        = (const float*)d_in[5];
    const float* b2        = (const float*)d_in[6];
    const float* sw        = (const float*)d_in[7];
    const float* sb        = (const float*)d_in[8];
    const float* dw        = (const float*)d_in[9];
    const float* db        = (const float*)d_in[10];

    char* ws = (char*)d_ws;
    _Float16* w1I = (_Float16*)ws;  ws += (size_t)512 * 13824 * 2;   // 14.2 MB
    _Float16* w2I = (_Float16*)ws;  ws += (size_t)512 * 27648 * 2;   // 28.3 MB
    _Float16* inI = (_Float16*)ws;  ws += (size_t)65536 * 512 * 2;   // 67.1 MB
    _Float16* x1I = (_Float16*)ws;  ws += (size_t)16384 * 1024 * 2;  // 33.5 MB
    float* scoreL = (float*)ws;     ws += (size_t)16 * 64 * 4;
    float* deltaL = (float*)ws;     ws += (size_t)16 * 64 * 4;
    float* zpage  = (float*)ws;     ws += (size_t)64 * 4;            // 256B zero page
    // x2p (4, 4096, 512) fp32 = 33.5 MB reuses the inI region (consumed by conv1)
    float* x2p = (float*)inI;

    prep_split<<<3072, 256, 0, stream>>>(w1, w1I, w2, w2I, base_feat, inI, zpage);
    conv1_mfma<<<512, 256, 0, stream>>>(inI, w1I, b1,
                                        (const _Float16*)zpage, x1I);
    conv2_mfma<<<512, 256, 0, stream>>>(x1I, w2I,
                                        (const _Float16*)zpage, x2p);
    feat_head<<<64, 256, 0, stream>>>(x2p, b2, sw, sb, dw, db, scoreL, deltaL);
    nms_loss_kernel<<<1, 64, 0, stream>>>(scoreL, deltaL, gt, video_len,
                                          (float*)d_out);
}

// Round 12
// 727.485 us; speedup vs baseline: 1.1161x; 1.1161x over previous
//
#include <hip/hip_runtime.h>

typedef __attribute__((ext_vector_type(8))) _Float16 half8;
typedef __attribute__((ext_vector_type(4))) _Float16 half4;
typedef __attribute__((ext_vector_type(4))) float floatx4;

#define DI __device__ __forceinline__

DI void gl_lds16(const void* g, void* l) {
    __builtin_amdgcn_global_load_lds(
        (__attribute__((address_space(1))) void*)(g),
        (__attribute__((address_space(3))) void*)(l), 16, 0, 0);
}

// Interleaved layout everywhere: per (row, ci32-block): [32 hi halfs | 32 lo halfs] = 128 B line.

// ------------- merged prep: weight split (b<1024) + input split (b>=1024) -------------
__global__ __launch_bounds__(256) void prep_split(
        const float* __restrict__ w1, _Float16* __restrict__ w1I,
        const float* __restrict__ w2, _Float16* __restrict__ w2I,
        const float* __restrict__ in, _Float16* __restrict__ oI,
        float* __restrict__ zp) {
    __shared__ float L[13824];
    const int b = blockIdx.x;
    const int tid = threadIdx.x;
    if (b == 0 && tid < 64) zp[tid] = 0.0f;      // 256B zero page for conv DMA OOB
    if (b < 512) {
        const float* src = w1 + (size_t)b * 6912;     // [ci=256][tap=27]
        for (int idx = tid; idx < 6912; idx += 256) L[idx] = src[idx] * 64.0f;
        __syncthreads();
        for (int c = tid; c < 864; c += 256) {        // 27 taps x 32 octets
            const int tap = c >> 5, o = c & 31;
            half8 h, l;
#pragma unroll
            for (int j = 0; j < 8; ++j) {
                const float x = L[(o * 8 + j) * 27 + tap];
                const _Float16 hh = (_Float16)x;
                h[j] = hh; l[j] = (_Float16)(x - (float)hh);
            }
            const size_t off = (size_t)b * 13824 + (size_t)(tap * 8 + (o >> 2)) * 64 + (o & 3) * 8;
            *(half8*)&w1I[off] = h;
            *(half8*)&w1I[off + 32] = l;
        }
    } else if (b < 1024) {
        const float* src = w2 + (size_t)(b - 512) * 13824;   // [ci=512][tap=27]
        for (int idx = tid; idx < 13824; idx += 256) L[idx] = src[idx] * 64.0f;
        __syncthreads();
        for (int c = tid; c < 1728; c += 256) {       // 27 taps x 64 octets
            const int tap = c >> 6, o = c & 63;
            half8 h, l;
#pragma unroll
            for (int j = 0; j < 8; ++j) {
                const float x = L[(o * 8 + j) * 27 + tap];
                const _Float16 hh = (_Float16)x;
                h[j] = hh; l[j] = (_Float16)(x - (float)hh);
            }
            const size_t off = (size_t)(b - 512) * 27648 + (size_t)(tap * 16 + (o >> 2)) * 64 + (o & 3) * 8;
            *(half8*)&w2I[off] = h;
            *(half8*)&w2I[off + 32] = l;
        }
    } else {
        const int idx = b - 1024;             // 0..2047
        const int hb = idx & 1;               // ci half
        const int s0 = (idx >> 1) * 64;       // spatial tile
        const int cil = tid >> 1, part = tid & 1;
        const float* src = in + (size_t)(hb * 128 + cil) * 65536 + s0 + part * 32;
        float v[32];
#pragma unroll
        for (int q = 0; q < 8; ++q) *(float4*)(v + q * 4) = *(const float4*)(src + q * 4);
#pragma unroll
        for (int j = 0; j < 32; ++j) L[cil * 65 + part * 32 + j] = v[j];
        __syncthreads();
#pragma unroll
        for (int k = 0; k < 4; ++k) {         // 64 sp x 16 local octets
            const int c = tid + k * 256;
            const int sp = c >> 4, ol = c & 15;
            half8 h, l;
#pragma unroll
            for (int j = 0; j < 8; ++j) {
                const float x = L[(ol * 8 + j) * 65 + sp];
                const _Float16 hh = (_Float16)x;
                h[j] = hh; l[j] = (_Float16)(x - (float)hh);
            }
            const int og = hb * 16 + ol;
            const size_t off = (size_t)(s0 + sp) * 512 + (size_t)(og >> 2) * 64 + (og & 3) * 8;
            *(half8*)&oI[off] = h;
            *(half8*)&oI[off + 32] = l;
        }
    }
}

// ---------- conv1: A+B dbuf DMA, drain-0 (waits ~0), B-fragment prefetch across barrier ----------
// grid n (0..511): XCD band n&7 = t>>3  ->  same-t blocks share an XCD's L2
__global__ __launch_bounds__(256, 2) void conv1_mfma(
        const _Float16* __restrict__ xI, const _Float16* __restrict__ wI,
        const float* __restrict__ b1, const _Float16* __restrict__ zp,
        _Float16* __restrict__ yI) {
    __shared__ __align__(16) _Float16 A2[2][128 * 64];   // 32 KB
    __shared__ __align__(16) _Float16 B2[2][128 * 64];   // 32 KB (64 KB total, 2 blocks/CU)
    const int tid = threadIdx.x;
    const int n_ = blockIdx.x;
    const int t = ((n_ & 7) << 3) | ((n_ >> 3) & 7);   // 0..63
    const int co_blk = (n_ >> 6) & 3;                  // 0..3
    const int h0 = ((n_ >> 8) & 1) * 8;                // 0 or 8
    const int wid = tid >> 6, lane = tid & 63;
    const int wm = wid & 1, wn = wid >> 1;
    const int ml = lane & 15, ql = lane >> 4;
    const int cs0 = (ql ^ (ml & 7)) * 8;          // hi chunk ql  (conflict-free pattern)
    const int cs1 = ((4 + ql) ^ (ml & 7)) * 8;    // lo chunk ql
    const int sl = lane & 7, rl = lane >> 3;
    const int lc = sl ^ rl;                        // logical chunk (mem offset lc*16B)

    const _Float16* wA[4]; const _Float16* bB[4];
    int dstq[4]; bool hok[4], wok[4];
    const size_t wbo = (size_t)co_blk * 128 * 13824;
#pragma unroll
    for (int q = 0; q < 4; ++q) {
        const int row = (q * 4 + wid) * 8 + rl;    // A: co row / B: n row
        wA[q] = wI + wbo + (size_t)row * 13824 + lc * 8;
        dstq[q] = (q * 4 + wid) * 512 + lane * 8;
        const int h = h0 + (row >> 4), w = row & 15;
        const int ih2 = 2 * h - 1, iw2 = 2 * w - 1;
        hok[q] = (ih2 >= 0); wok[q] = (iw2 >= 0);  // only edge underflow possible
        bB[q] = xI + (ptrdiff_t)(ih2 * 32 + iw2) * 512 + lc * 8;
    }
    const _Float16* zpl = zp + lc * 8;

    floatx4 zz = {0.f, 0.f, 0.f, 0.f};
    floatx4 acc[4][4];
#pragma unroll
    for (int i = 0; i < 4; ++i)
#pragma unroll
        for (int j = 0; j < 4; ++j) acc[i][j] = zz;

    auto stageA = [&](int kt, int cb, int KH, int KW, _Float16* Ad) {
        const size_t ab = (size_t)(((kt * 9 + KH * 3 + KW) * 8 + cb) * 64);
#pragma unroll
        for (int q = 0; q < 4; ++q) gl_lds16(wA[q] + ab, &Ad[dstq[q]]);
    };
    auto stageB = [&](int kt, int cb, int KH, int KW, _Float16* Bd) {
        const int it = t + kt - 1;                      // wave-uniform
        const bool tok = ((unsigned)it < 64u);
        const ptrdiff_t boff = (ptrdiff_t)it * 524288 + KH * 16384 + KW * 512 + cb * 64;
#pragma unroll
        for (int q = 0; q < 4; ++q) {
            const bool ok = tok && (KH > 0 || hok[q]) && (KW > 0 || wok[q]);
            gl_lds16(ok ? (bB[q] + boff) : zpl, &Bd[dstq[q]]);
        }
    };

    // B fragments for the CURRENT phase, prefetched during the previous phase
    half8 bh8c[4], bloc[4];

    // prologue: phase 0 fully staged + its B fragments prefetched
    stageA(0, 0, 0, 0, A2[0]);
    stageB(0, 0, 0, 0, B2[0]);
    asm volatile("s_waitcnt vmcnt(0)" ::: "memory");
    __builtin_amdgcn_s_barrier();
#pragma unroll
    for (int ni = 0; ni < 4; ++ni) {
        bh8c[ni] = *(const half8*)&B2[0][(wn * 64 + ni * 16 + ml) * 64 + cs0];
        bloc[ni] = *(const half8*)&B2[0][(wn * 64 + ni * 16 + ml) * 64 + cs1];
    }

    for (int o = 0; o < 24; ++o) {                 // o = cb*3 + kt
        const int cb = o / 3, kt = o - cb * 3;
        const int o1 = o + 1;
        const int cb1 = o1 / 3, kt1 = o1 - cb1 * 3;   // o==23 -> dummy-but-valid addresses
#pragma unroll
        for (int j = 0; j < 9; ++j) {              // j = kh*3 + kw (compile-time)
            const int par = (o + j) & 1;           // current buffers
            // issue stage for phase p+1 into [par^1] (lands by this phase's end)
            if (j < 8) {
                stageA(kt, cb, (j + 1) / 3, (j + 1) % 3, A2[par ^ 1]);
                stageB(kt, cb, (j + 1) / 3, (j + 1) % 3, B2[par ^ 1]);
            } else {
                stageA(kt1, cb1, 0, 0, A2[par ^ 1]);
                stageB(kt1, cb1, 0, 0, B2[par ^ 1]);
            }
            // A fragments for phase p (B fragments already in registers)
            const _Float16* Ab = A2[par];
            half8 ah[4], alo[4];
#pragma unroll
            for (int mi = 0; mi < 4; ++mi) {
                ah[mi]  = *(const half8*)&Ab[(wm * 64 + mi * 16 + ml) * 64 + cs0];
                alo[mi] = *(const half8*)&Ab[(wm * 64 + mi * 16 + ml) * 64 + cs1];
            }
            __builtin_amdgcn_s_setprio(1);
#pragma unroll
            for (int mi = 0; mi < 4; ++mi)
#pragma unroll
                for (int ni = 0; ni < 4; ++ni) {
                    acc[mi][ni] = __builtin_amdgcn_mfma_f32_16x16x32_f16(ah[mi],  bh8c[ni], acc[mi][ni], 0, 0, 0);
                    acc[mi][ni] = __builtin_amdgcn_mfma_f32_16x16x32_f16(ah[mi],  bloc[ni], acc[mi][ni], 0, 0, 0);
                    acc[mi][ni] = __builtin_amdgcn_mfma_f32_16x16x32_f16(alo[mi], bh8c[ni], acc[mi][ni], 0, 0, 0);
                }
            __builtin_amdgcn_s_setprio(0);
            // drain (waits ~0: staged at phase start, a full phase ago) + barrier
            asm volatile("s_waitcnt vmcnt(0)" ::: "memory");
            __builtin_amdgcn_s_barrier();
            // prefetch B fragments for phase p+1 from the just-drained buffer
            const _Float16* Bn = B2[par ^ 1];
#pragma unroll
            for (int ni = 0; ni < 4; ++ni) {
                bh8c[ni] = *(const half8*)&Bn[(wn * 64 + ni * 16 + ml) * 64 + cs0];
                bloc[ni] = *(const half8*)&Bn[(wn * 64 + ni * 16 + ml) * 64 + cs1];
            }
        }
    }

    // epilogue: unscale, +bias, hi/lo split, interleaved store (sp2*1024 + cb*64 + k)
    const int qr = ql * 4;
#pragma unroll
    for (int mi = 0; mi < 4; ++mi) {
        const int co = co_blk * 128 + wm * 64 + mi * 16 + qr;
#pragma unroll
        for (int ni = 0; ni < 4; ++ni) {
            const int n = wn * 64 + ni * 16 + ml;
            const int h = h0 + (n >> 4), w = n & 15;
            const size_t base = ((size_t)t * 256 + h * 16 + w) * 1024
                              + (size_t)(co >> 5) * 64 + (co & 31);
            half4 hv, lv;
#pragma unroll
            for (int r = 0; r < 4; ++r) {
                const float v = acc[mi][ni][r] * 0.015625f + b1[co + r];
                const _Float16 hb = (_Float16)v;
                hv[r] = hb;
                lv[r] = (_Float16)(v - (float)hb);
            }
            *(half4*)(yI + base) = hv;
            *(half4*)(yI + base + 32) = lv;
        }
    }
}

// ---------- conv2: A+B dbuf DMA, drain-0, B-fragment prefetch, XCD-banded ----------
// grid n (0..511): XCD band n&7 = tp>>2 -> same-tp blocks (all co, ks) share an XCD's L2
__global__ __launch_bounds__(256, 2) void conv2_mfma(
        const _Float16* __restrict__ xI, const _Float16* __restrict__ wI,
        const _Float16* __restrict__ zp,
        float* __restrict__ x2p) {
    __shared__ __align__(16) _Float16 A2[2][128 * 64];
    __shared__ __align__(16) _Float16 B2[2][128 * 64];
    const int tid = threadIdx.x;
    const int n_ = blockIdx.x;
    const int tp = ((n_ & 7) << 2) | ((n_ >> 3) & 3);  // 0..31
    const int co_blk = (n_ >> 5) & 3;                  // 0..3
    const int ks = (n_ >> 7) & 3;                      // 0..3
    const int wid = tid >> 6, lane = tid & 63;
    const int wm = wid & 1, wn = wid >> 1;
    const int ml = lane & 15, ql = lane >> 4;
    const int cs0 = (ql ^ (ml & 7)) * 8;
    const int cs1 = ((4 + ql) ^ (ml & 7)) * 8;
    const int sl = lane & 7, rl = lane >> 3;
    const int lc = sl ^ rl;

    const _Float16* wA[4]; const _Float16* bB[4];
    int dstq[4], itv[4]; bool hok[4], wok[4];
    const size_t wbo = (size_t)co_blk * 128 * 27648;
#pragma unroll
    for (int q = 0; q < 4; ++q) {
        const int row = (q * 4 + wid) * 8 + rl;
        wA[q] = wI + wbo + (size_t)row * 27648 + lc * 8;
        dstq[q] = (q * 4 + wid) * 512 + lane * 8;
        const int sp = row & 63;
        itv[q] = tp * 2 + (row >> 6) - 1;
        const int ih2 = 2 * (sp >> 3) - 1, iw2 = 2 * (sp & 7) - 1;
        hok[q] = (ih2 >= 0); wok[q] = (iw2 >= 0);
        bB[q] = xI + (ptrdiff_t)((itv[q] * 256 + ih2 * 16 + iw2) * 1024) + lc * 8;
    }
    const _Float16* zpl = zp + lc * 8;

    floatx4 zz = {0.f, 0.f, 0.f, 0.f};
    floatx4 acc[4][4];
#pragma unroll
    for (int i = 0; i < 4; ++i)
#pragma unroll
        for (int j = 0; j < 4; ++j) acc[i][j] = zz;

    auto stageA = [&](int kt, int cb, int KH, int KW, _Float16* Ad) {
        const size_t ab = (size_t)(((kt * 9 + KH * 3 + KW) * 16 + cb) * 64);
#pragma unroll
        for (int q = 0; q < 4; ++q) gl_lds16(wA[q] + ab, &Ad[dstq[q]]);
    };
    auto stageB = [&](int kt, int cb, int KH, int KW, _Float16* Bd) {
        const ptrdiff_t boff = (ptrdiff_t)kt * 262144 + KH * 16384 + KW * 1024 + cb * 64;
#pragma unroll
        for (int q = 0; q < 4; ++q) {
            const bool ok = ((unsigned)(itv[q] + kt) < 64u)
                         && (KH > 0 || hok[q]) && (KW > 0 || wok[q]);
            gl_lds16(ok ? (bB[q] + boff) : zpl, &Bd[dstq[q]]);
        }
    };

    half8 bh8c[4], bloc[4];

    stageA(0, ks * 4, 0, 0, A2[0]);
    stageB(0, ks * 4, 0, 0, B2[0]);
    asm volatile("s_waitcnt vmcnt(0)" ::: "memory");
    __builtin_amdgcn_s_barrier();
#pragma unroll
    for (int ni = 0; ni < 4; ++ni) {
        bh8c[ni] = *(const half8*)&B2[0][(wn * 64 + ni * 16 + ml) * 64 + cs0];
        bloc[ni] = *(const half8*)&B2[0][(wn * 64 + ni * 16 + ml) * 64 + cs1];
    }

    for (int o = 0; o < 12; ++o) {
        const int kt = o % 3, cb = ks * 4 + o / 3;
        const int o1 = o + 1;
        const int kt1 = o1 % 3, cb1 = ks * 4 + o1 / 3;   // o==11 -> dummy-but-valid
#pragma unroll
        for (int j = 0; j < 9; ++j) {
            const int par = (o + j) & 1;
            if (j < 8) {
                stageA(kt, cb, (j + 1) / 3, (j + 1) % 3, A2[par ^ 1]);
                stageB(kt, cb, (j + 1) / 3, (j + 1) % 3, B2[par ^ 1]);
            } else {
                stageA(kt1, cb1, 0, 0, A2[par ^ 1]);
                stageB(kt1, cb1, 0, 0, B2[par ^ 1]);
            }
            const _Float16* Ab = A2[par];
            half8 ah[4], alo[4];
#pragma unroll
            for (int mi = 0; mi < 4; ++mi) {
                ah[mi]  = *(const half8*)&Ab[(wm * 64 + mi * 16 + ml) * 64 + cs0];
                alo[mi] = *(const half8*)&Ab[(wm * 64 + mi * 16 + ml) * 64 + cs1];
            }
            __builtin_amdgcn_s_setprio(1);
#pragma unroll
            for (int mi = 0; mi < 4; ++mi)
#pragma unroll
                for (int ni = 0; ni < 4; ++ni) {
                    acc[mi][ni] = __builtin_amdgcn_mfma_f32_16x16x32_f16(ah[mi],  bh8c[ni], acc[mi][ni], 0, 0, 0);
                    acc[mi][ni] = __builtin_amdgcn_mfma_f32_16x16x32_f16(ah[mi],  bloc[ni], acc[mi][ni], 0, 0, 0);
                    acc[mi][ni] = __builtin_amdgcn_mfma_f32_16x16x32_f16(alo[mi], bh8c[ni], acc[mi][ni], 0, 0, 0);
                }
            __builtin_amdgcn_s_setprio(0);
            asm volatile("s_waitcnt vmcnt(0)" ::: "memory");
            __builtin_amdgcn_s_barrier();
            const _Float16* Bn = B2[par ^ 1];
#pragma unroll
            for (int ni = 0; ni < 4; ++ni) {
                bh8c[ni] = *(const half8*)&Bn[(wn * 64 + ni * 16 + ml) * 64 + cs0];
                bloc[ni] = *(const half8*)&Bn[(wn * 64 + ni * 16 + ml) * 64 + cs1];
            }
        }
    }

    const int qr = ql * 4;
#pragma unroll
    for (int mi = 0; mi < 4; ++mi) {
        const int co = co_blk * 128 + wm * 64 + mi * 16 + qr;
#pragma unroll
        for (int ni = 0; ni < 4; ++ni) {
            const int n = wn * 64 + ni * 16 + ml;
            const int ng = tp * 128 + n;
            float4 v;
            v.x = acc[mi][ni][0]; v.y = acc[mi][ni][1];
            v.z = acc[mi][ni][2]; v.w = acc[mi][ni][3];
            *(float4*)&x2p[((size_t)ks * 4096 + ng) * 512 + co] = v;
        }
    }
}

// ------------- fused feat (K-split sum + spatial max + bias) and head matvec -------------
__global__ __launch_bounds__(256) void feat_head(
        const float* __restrict__ x2p, const float* __restrict__ b2,
        const float* __restrict__ sw, const float* __restrict__ sb,
        const float* __restrict__ dw, const float* __restrict__ db,
        float* __restrict__ scoreL, float* __restrict__ deltaL) {
    __shared__ float fr[512];
    __shared__ float partial[32][8];
    const int t = blockIdx.x, tid = threadIdx.x;
#pragma unroll
    for (int cc = 0; cc < 2; ++cc) {
        const int c = tid + cc * 256;
        float mx = -3.4e38f;
        for (int sp = 0; sp < 64; ++sp) {
            const size_t ng = (size_t)t * 64 + sp;
            const float s = x2p[ng * 512 + c]
                          + x2p[((size_t)4096 + ng) * 512 + c]
                          + x2p[((size_t)8192 + ng) * 512 + c]
                          + x2p[((size_t)12288 + ng) * 512 + c];
            mx = fmaxf(mx, s);
        }
        fr[c] = mx * 0.015625f + b2[c];
    }
    __syncthreads();
    const int o = tid & 31, part = tid >> 5;
    const float* wrow = (o < 16) ? (sw + (size_t)o * 512) : (dw + (size_t)(o - 16) * 512);
    float s = 0.f;
    const int j0 = part * 64;
#pragma unroll 16
    for (int j = 0; j < 64; ++j) s += wrow[j0 + j] * fr[j0 + j];
    partial[o][part] = s;
    __syncthreads();
    if (tid < 32) {
        float tot = 0.f;
#pragma unroll
        for (int p = 0; p < 8; ++p) tot += partial[tid][p];
        tot += (tid < 16) ? sb[tid] : db[tid - 16];
        if (tid < 16) scoreL[tid * 64 + t] = tot;
        else deltaL[(tid - 16) * 64 + t] = tot;
    }
}

// ------------- NMS + labels + losses: SINGLE WAVE (64 lanes), no barriers -------------
__global__ void nms_loss_kernel(const float* __restrict__ scoreL,
                                const float* __restrict__ deltaL,
                                const float* __restrict__ gt,
                                const int* __restrict__ video_len,
                                float* __restrict__ out) {
    const int lane = threadIdx.x & 63;
    float gsv[8], gev[8];
#pragma unroll
    for (int g = 0; g < 8; ++g) { gsv[g] = gt[2 * g]; gev[g] = gt[2 * g + 1]; }
    const float center = ((float)lane + 0.5f) * 8.0f;
    float psv[8], pev[8], fg[8], l0v[8], l1v[8], dcv[8], dlv[8];
#pragma unroll
    for (int j = 0; j < 8; ++j) {
        const float s0 = scoreL[j * 64 + lane], s1 = scoreL[(8 + j) * 64 + lane];
        const float mm = fmaxf(s0, s1);
        const float lse = mm + logf(expf(s0 - mm) + expf(s1 - mm));
        l0v[j] = s0 - lse; l1v[j] = s1 - lse;
        const float dc = deltaL[j * 64 + lane], dl = deltaL[(8 + j) * 64 + lane];
        dcv[j] = dc; dlv[j] = dl;
        const float alen = 8.0f * (float)(1 << j);
        const float pc = center + dc * alen;
        const float pl = alen * expf(fminf(fmaxf(dl, -10.0f), 10.0f));
        const float ps = fminf(fmaxf(pc - pl * 0.5f, 0.0f), 512.0f);
        const float pe = fminf(fmaxf(pc + pl * 0.5f, 0.0f), 512.0f);
        psv[j] = ps; pev[j] = pe;
        fg[j] = ((pe - ps) >= 4.0f) ? expf(l1v[j]) : -1e9f;
    }
    for (int itn = 0; itn < 100; ++itn) {
        float v = fg[0]; int idx = lane;
#pragma unroll
        for (int j = 1; j < 8; ++j) if (fg[j] > v) { v = fg[j]; idx = lane + 64 * j; }
#pragma unroll
        for (int off = 32; off > 0; off >>= 1) {
            const float ov = __shfl_down(v, off);
            const int oi = __shfl_down(idx, off);
            if (ov > v || (ov == v && oi < idx)) { v = ov; idx = oi; }
        }
        v = __shfl(v, 0); idx = __shfl(idx, 0);
        const int wj = idx >> 6, wl = idx & 63;
        float bw0 = 0.f, bw1 = 0.f;
#pragma unroll
        for (int j = 0; j < 8; ++j) if (j == wj) { bw0 = psv[j]; bw1 = pev[j]; }
        const float b0 = __shfl(bw0, wl);
        const float b1 = __shfl(bw1, wl);
        if (lane == 0) {
            const bool kept = v > -5e8f;
            out[2 * itn] = kept ? b0 : 0.0f;
            out[2 * itn + 1] = kept ? b1 : 0.0f;
            out[200 + itn] = kept ? v : 0.0f;
        }
#pragma unroll
        for (int j = 0; j < 8; ++j) {
            const int n = lane + 64 * j;
            const float inter = fmaxf(fminf(b1, pev[j]) - fmaxf(b0, psv[j]), 0.0f);
            const float uni = (b1 - b0) + (pev[j] - psv[j]) - inter;
            const float iou = inter / fmaxf(uni, 1e-6f);
            if (iou > 0.7f || n == idx) fg[j] = -1e9f;
        }
    }
    int labv[8], aggv[8];
#pragma unroll
    for (int j = 0; j < 8; ++j) {
        const float alen = 8.0f * (float)(1 << j);
        const float as_ = center - alen * 0.5f, ae_ = center + alen * 0.5f;
        float mx = -1.0f; int ag = 0;
#pragma unroll
        for (int g = 0; g < 8; ++g) {
            const float inter = fmaxf(fminf(ae_, gev[g]) - fmaxf(as_, gsv[g]), 0.0f);
            const float uni = (ae_ - as_) + (gev[g] - gsv[g]) - inter;
            const float iou = inter / fmaxf(uni, 1e-6f);
            if (iou > mx) { mx = iou; ag = g; }
        }
        labv[j] = (mx < 0.3f) ? 0 : ((mx >= 0.7f) ? 1 : -1);
        aggv[j] = ag;
    }
    for (int g = 0; g < 8; ++g) {
        float v = -1.0f; int idx = 0;
#pragma unroll
        for (int j = 0; j < 8; ++j) {
            const int n = lane + 64 * j;
            const float alen = 8.0f * (float)(1 << j);
            const float as_ = center - alen * 0.5f, ae_ = center + alen * 0.5f;
            const float inter = fmaxf(fminf(ae_, gev[g]) - fmaxf(as_, gsv[g]), 0.0f);
            const float uni = (ae_ - as_) + (gev[g] - gsv[g]) - inter;
            const float iou = inter / fmaxf(uni, 1e-6f);
            if (iou > v || (iou == v && n < idx)) { v = iou; idx = n; }
        }
#pragma unroll
        for (int off = 32; off > 0; off >>= 1) {
            const float ov = __shfl_down(v, off);
            const int oi = __shfl_down(idx, off);
            if (ov > v || (ov == v && oi < idx)) { v = ov; idx = oi; }
        }
        idx = __shfl(idx, 0);
#pragma unroll
        for (int j = 0; j < 8; ++j)
            if (lane == (idx & 63) && j == (idx >> 6)) labv[j] = 1;
    }
    const float vl = (float)video_len[0];
    float nll_s = 0.f, msk_s = 0.f, reg_s = 0.f, pos_s = 0.f;
#pragma unroll
    for (int j = 0; j < 8; ++j) {
        const float alen = 8.0f * (float)(1 << j);
        const float as_ = center - alen * 0.5f, ae_ = center + alen * 0.5f;
        int l = labv[j];
        if (!((as_ >= 0.0f) && (ae_ <= vl))) l = -1;
        if (l >= 0) {
            msk_s += 1.0f;
            nll_s -= (l == 1) ? l1v[j] : l0v[j];
            if (l == 1) {
                pos_s += 1.0f;
                float gcv = 0.f, glv = 0.f;
#pragma unroll
                for (int g = 0; g < 8; ++g)
                    if (g == aggv[j]) {
                        gcv = (gsv[g] + gev[g]) * 0.5f;
                        glv = fmaxf(gev[g] - gsv[g], 1e-6f);
                    }
                const float r0 = (gcv - center) / alen;
                const float r1 = logf(glv / alen);
                const float d0 = dcv[j] - r0, d1 = dlv[j] - r1;
                float s = (fabsf(d0) < 1.0f) ? (0.5f * d0 * d0) : (fabsf(d0) - 0.5f);
                s += (fabsf(d1) < 1.0f) ? (0.5f * d1 * d1) : (fabsf(d1) - 0.5f);
                reg_s += s;
            }
        }
    }
    float sums[4] = {nll_s, msk_s, reg_s, pos_s};
#pragma unroll
    for (int k = 0; k < 4; ++k)
#pragma unroll
        for (int off = 32; off > 0; off >>= 1) sums[k] += __shfl_down(sums[k], off);
    if (lane == 0) {
        out[300] = sums[0] / fmaxf(sums[1], 1.0f);
        out[301] = sums[2] / fmaxf(sums[3], 1.0f);
    }
}

extern "C" void kernel_launch(void* const* d_in, const int* in_sizes, int n_in,
                              void* d_out, int out_size, void* d_ws, size_t ws_size,
                              hipStream_t stream) {
    const float* base_feat = (const float*)d_in[0];
    const float* gt        = (const float*)d_in[1];
    const int*   video_len = (const int*)d_in[2];
    const float* w1        = (const float*)d_in[3];
    const float* b1        = (const float*)d_in[4];
    const float* w2        = (const float*)d_in[5];
    const float* b2        = (const float*)d_in[6];
    const float* sw        = (const float*)d_in[7];
    const float* sb        = (const float*)d_in[8];
    const float* dw        = (const float*)d_in[9];
    const float* db        = (const float*)d_in[10];

    char* ws = (char*)d_ws;
    _Float16* w1I = (_Float16*)ws;  ws += (size_t)512 * 13824 * 2;   // 14.2 MB
    _Float16* w2I = (_Float16*)ws;  ws += (size_t)512 * 27648 * 2;   // 28.3 MB
    _Float16* inI = (_Float16*)ws;  ws += (size_t)65536 * 512 * 2;   // 67.1 MB
    _Float16* x1I = (_Float16*)ws;  ws += (size_t)16384 * 1024 * 2;  // 33.5 MB
    float* scoreL = (float*)ws;     ws += (size_t)16 * 64 * 4;
    float* deltaL = (float*)ws;     ws += (size_t)16 * 64 * 4;
    float* zpage  = (float*)ws;     ws += (size_t)64 * 4;            // 256B zero page
    // x2p (4, 4096, 512) fp32 = 33.5 MB reuses the inI region (consumed by conv1)
    float* x2p = (float*)inI;

    prep_split<<<3072, 256, 0, stream>>>(w1, w1I, w2, w2I, base_feat, inI, zpage);
    conv1_mfma<<<512, 256, 0, stream>>>(inI, w1I, b1,
                                        (const _Float16*)zpage, x1I);
    conv2_mfma<<<512, 256, 0, stream>>>(x1I, w2I,
                                        (const _Float16*)zpage, x2p);
    feat_head<<<64, 256, 0, stream>>>(x2p, b2, sw, sb, dw, db, scoreL, deltaL);
    nms_loss_kernel<<<1, 64, 0, stream>>>(scoreL, deltaL, gt, video_len,
                                          (float*)d_out);
}